// Round 4
// baseline (221.536 us; speedup 1.0000x reference)
//
#include <hip/hip_runtime.h>
#include <hip/hip_bf16.h>
#include <math.h>

typedef unsigned short ushort_t;
typedef __attribute__((ext_vector_type(8))) short bf16x8;
typedef __attribute__((ext_vector_type(4))) float f32x4;

constexpr int BATCH   = 4;
constexpr int LEN_IN  = 5440;
constexpr int LEN_Q   = 5440;
constexpr int M_TOT   = BATCH * LEN_Q;   // 21760

__device__ __forceinline__ ushort_t bfbits(float x) {
    __hip_bfloat16 h = __float2bfloat16(x);
    ushort_t u; __builtin_memcpy(&u, &h, 2); return u;
}
__device__ __forceinline__ unsigned pk2(float a, float b) {
    return (unsigned)bfbits(a) | ((unsigned)bfbits(b) << 16);
}

// ======================= weight pack / transpose (tiny) =======================
// blocks [0,32)   : W_val  [256k,256n] -> wvT  [256n][256k] bf16
// blocks [32,64)  : W_out  -> woutT
// blocks [64,112) : W_off|W_attn -> woaT [384n][256k] bf16
// block  112      : bias concat (b_off | b_attn)
__global__ __launch_bounds__(256) void pack_w(
    const float* __restrict__ Wv, const float* __restrict__ Wo,
    const float* __restrict__ Wa, const float* __restrict__ Wout,
    const float* __restrict__ b_off, const float* __restrict__ b_attn,
    ushort_t* __restrict__ wvT, ushort_t* __restrict__ woaT,
    ushort_t* __restrict__ woutT, float* __restrict__ bias_oa)
{
    const int blk = blockIdx.x, tid = threadIdx.x;
    if (blk < 64) {
        const float* src = (blk < 32) ? Wv : Wout;
        ushort_t*    dst = (blk < 32) ? wvT : woutT;
        const int base = (blk & 31) * 2048;
#pragma unroll
        for (int i = 0; i < 8; i++) {
            const int idx = base + i * 256 + tid;
            const int k = idx >> 8, n = idx & 255;
            dst[n * 256 + k] = bfbits(src[idx]);
        }
    } else if (blk < 112) {
        const int base = (blk - 64) * 2048;
#pragma unroll
        for (int i = 0; i < 8; i++) {
            const int idx = base + i * 256 + tid;   // < 98304
            const int k = idx / 384, j = idx - k * 384;
            const float v = (j < 256) ? Wo[k * 256 + j] : Wa[k * 128 + (j - 256)];
            woaT[j * 256 + k] = bfbits(v);
        }
    } else {
        bias_oa[tid] = b_off[tid];
        if (tid < 128) bias_oa[256 + tid] = b_attn[tid];
    }
}

// ======================= bf16 MFMA GEMM core =======================
// C[M,N] = A[M,256] @ BT[N,256]^T + bias[N].  A is fp32 (converted during
// staging) or bf16.  128x128 tile, BK=32, 256 thr (4 waves), 4x4
// mfma_f32_16x16x32_bf16 per wave.  Epilogue: per-wave LDS transpose
// (stride 68 -> <=2-way banks) then dwordx4 coalesced stores.
template <bool A_F32, bool OUT_BF16>
__device__ __forceinline__ void gemm_core(
    const void* __restrict__ Ap, const ushort_t* __restrict__ BT,
    const float* __restrict__ bias, void* __restrict__ Cp, int N,
    int bm, int bn, ushort_t* SMEM)
{
    ushort_t* As = SMEM;          // [128][32] bf16
    ushort_t* Bs = SMEM + 4096;   // [128][32] bf16
    const int tid  = threadIdx.x;
    const int wave = tid >> 6, lane = tid & 63;
    const int wm = (wave >> 1) * 64, wn = (wave & 1) * 64;
    const int srow = tid >> 1, skh = (tid & 1) * 16;
    const int row16 = lane & 15, kg = (lane >> 4) * 8;

    f32x4 acc[4][4] = {};

    for (int kt = 0; kt < 8; kt++) {
        const int k0 = kt * 32;
        uint4 a0, a1;
        if (A_F32) {
            const float* ap = (const float*)Ap + (size_t)(bm + srow) * 256 + k0 + skh;
            float4 f0 = *(const float4*)(ap);
            float4 f1 = *(const float4*)(ap + 4);
            float4 f2 = *(const float4*)(ap + 8);
            float4 f3 = *(const float4*)(ap + 12);
            a0.x = pk2(f0.x, f0.y); a0.y = pk2(f0.z, f0.w);
            a0.z = pk2(f1.x, f1.y); a0.w = pk2(f1.z, f1.w);
            a1.x = pk2(f2.x, f2.y); a1.y = pk2(f2.z, f2.w);
            a1.z = pk2(f3.x, f3.y); a1.w = pk2(f3.z, f3.w);
        } else {
            const ushort_t* ap = (const ushort_t*)Ap + (size_t)(bm + srow) * 256 + k0 + skh;
            a0 = ((const uint4*)ap)[0];
            a1 = ((const uint4*)ap)[1];
        }
        const ushort_t* bp = BT + (size_t)(bn + srow) * 256 + k0 + skh;
        uint4 b0 = ((const uint4*)bp)[0];
        uint4 b1 = ((const uint4*)bp)[1];
        __syncthreads();
        *(uint4*)(As + srow * 32 + skh)     = a0;
        *(uint4*)(As + srow * 32 + skh + 8) = a1;
        *(uint4*)(Bs + srow * 32 + skh)     = b0;
        *(uint4*)(Bs + srow * 32 + skh + 8) = b1;
        __syncthreads();
        bf16x8 af[4], bfr[4];
#pragma unroll
        for (int i = 0; i < 4; i++)
            af[i] = *(const bf16x8*)(As + (wm + i * 16 + row16) * 32 + kg);
#pragma unroll
        for (int j = 0; j < 4; j++)
            bfr[j] = *(const bf16x8*)(Bs + (wn + j * 16 + row16) * 32 + kg);
#pragma unroll
        for (int i = 0; i < 4; i++)
#pragma unroll
            for (int j = 0; j < 4; j++)
                acc[i][j] = __builtin_amdgcn_mfma_f32_16x16x32_bf16(
                    af[i], bfr[j], acc[i][j], 0, 0, 0);
    }

    // ---- epilogue: LDS transpose then wide coalesced stores ----
    float* sw = (float*)SMEM + wave * (16 * 68);   // 16 rows x 68 (pad) floats
    const int rb4 = (lane >> 4) * 4;
    float bv[4];
#pragma unroll
    for (int j = 0; j < 4; j++) bv[j] = bias[bn + wn + j * 16 + row16];
    const int err = lane >> 2;          // 0..15 read row
    const int ecs = (lane & 3) * 16;    // col segment

#pragma unroll
    for (int i = 0; i < 4; i++) {
        __syncthreads();   // protect LDS reuse (k-loop frags / previous i)
#pragma unroll
        for (int j = 0; j < 4; j++)
#pragma unroll
            for (int r = 0; r < 4; r++)
                sw[(rb4 + r) * 68 + j * 16 + row16] = acc[i][j][r] + bv[j];
        __syncthreads();
        const float* rp = sw + err * 68 + ecs;
        f32x4 v0 = ((const f32x4*)rp)[0];
        f32x4 v1 = ((const f32x4*)rp)[1];
        f32x4 v2 = ((const f32x4*)rp)[2];
        f32x4 v3 = ((const f32x4*)rp)[3];
        const int grow = bm + wm + i * 16 + err;
        if (OUT_BF16) {
            ushort_t* cp = (ushort_t*)Cp + (size_t)grow * N + bn + wn + ecs;
            uint4 o0, o1;
            o0.x = pk2(v0[0], v0[1]); o0.y = pk2(v0[2], v0[3]);
            o0.z = pk2(v1[0], v1[1]); o0.w = pk2(v1[2], v1[3]);
            o1.x = pk2(v2[0], v2[1]); o1.y = pk2(v2[2], v2[3]);
            o1.z = pk2(v3[0], v3[1]); o1.w = pk2(v3[2], v3[3]);
            ((uint4*)cp)[0] = o0;
            ((uint4*)cp)[1] = o1;
        } else {
            float* cp = (float*)Cp + (size_t)grow * N + bn + wn + ecs;
            ((f32x4*)cp)[0] = v0;
            ((f32x4*)cp)[1] = v1;
            ((f32x4*)cp)[2] = v2;
            ((f32x4*)cp)[3] = v3;
        }
    }
}

// LDS: max(staging 16 KB, scratch 4 waves * 16*68*4 = 17408 B)
constexpr int SMEM_USHORTS = 4 * 16 * 68 * 2;   // 17408 B

// [0,340)   : value  = in_flat(f32) @ wvT  -> bf16, N=256
// [340,850) : offattn= query(f32)   @ woaT -> f32,  N=384
__global__ __launch_bounds__(256) void gemm_dual(
    const float* __restrict__ inflat, const ushort_t* __restrict__ wvT,
    const float* __restrict__ b_val, ushort_t* __restrict__ value_bf,
    const float* __restrict__ query, const ushort_t* __restrict__ woaT,
    const float* __restrict__ bias_oa, float* __restrict__ offattn)
{
    __shared__ ushort_t SMEM[SMEM_USHORTS];
    int blk = blockIdx.x;
    if (blk < 340) {
        const int bn = (blk & 1) * 128, bm = (blk >> 1) * 128;
        gemm_core<true, true>(inflat, wvT, b_val, value_bf, 256, bm, bn, SMEM);
    } else {
        blk -= 340;
        const int bn = (blk % 3) * 128, bm = (blk / 3) * 128;
        gemm_core<true, false>(query, woaT, bias_oa, offattn, 384, bm, bn, SMEM);
    }
}

__global__ __launch_bounds__(256) void gemm_out(
    const ushort_t* __restrict__ mid_bf, const ushort_t* __restrict__ woutT,
    const float* __restrict__ b_out, float* __restrict__ out)
{
    __shared__ ushort_t SMEM[SMEM_USHORTS];
    const int bn = (blockIdx.x & 1) * 128, bm = (blockIdx.x >> 1) * 128;
    gemm_core<false, false>(mid_bf, woutT, b_out, out, 256, bm, bn, SMEM);
}

// ======================= softmax + bilinear sampling =======================
// 256 thr = 8 queries x (8 heads x 4 lanes); lane owns 8 bf16 channels (16 B).
// Depth-2 software pipeline: compute+load point p+1 before accumulating p.
__device__ __forceinline__ void acc8(float* acc, uint4 v, float w) {
    const unsigned* p = &v.x;
#pragma unroll
    for (int d = 0; d < 4; d++) {
        const unsigned u = p[d];
        const float lo = __uint_as_float(u << 16);
        const float hi = __uint_as_float(u & 0xFFFF0000u);
        acc[2 * d]     = fmaf(w, lo, acc[2 * d]);
        acc[2 * d + 1] = fmaf(w, hi, acc[2 * d + 1]);
    }
}

__global__ __launch_bounds__(256) void msda_sample_bf16(
    const ushort_t* __restrict__ value, const float* __restrict__ refp,
    const float* __restrict__ offattn, ushort_t* __restrict__ mid)
{
    constexpr int LVL_H[4]  = {64, 32, 16, 8};
    constexpr int LVL_W[4]  = {64, 32, 16, 8};
    constexpr int LVL_ST[4] = {0, 4096, 5120, 5376};

    const int tid  = threadIdx.x;
    const int bq   = blockIdx.x * 8 + (tid >> 5);
    const int b    = bq / LEN_Q;
    const int t32  = tid & 31;
    const int head = t32 >> 2;
    const int c8   = (t32 & 3) * 8;

    const float* base = offattn + (size_t)bq * 384;
    const float* lp = base + 256 + head * 16;
    float4 l0 = ((const float4*)lp)[0];
    float4 l1 = ((const float4*)lp)[1];
    float4 l2 = ((const float4*)lp)[2];
    float4 l3 = ((const float4*)lp)[3];
    float lg[16] = {l0.x, l0.y, l0.z, l0.w, l1.x, l1.y, l1.z, l1.w,
                    l2.x, l2.y, l2.z, l2.w, l3.x, l3.y, l3.z, l3.w};
    float mx = lg[0];
#pragma unroll
    for (int j = 1; j < 16; j++) mx = fmaxf(mx, lg[j]);

    const float* op = base + head * 32;
    float4 ov[8];
#pragma unroll
    for (int j = 0; j < 8; j++) ov[j] = ((const float4*)op)[j];
    const float* rp = refp + (size_t)bq * 8;
    float4 r0 = ((const float4*)rp)[0];
    float4 r1 = ((const float4*)rp)[1];
    const float rx[4] = {r0.x, r0.z, r1.x, r1.z};
    const float ry[4] = {r0.y, r0.w, r1.y, r1.w};

    const ushort_t* vbase = value + (size_t)b * LEN_IN * 256 + head * 32 + c8;

    float acc[8] = {};
    float esum = 0.f;

    // pipeline state (stage = pi & 1)
    int   A00[2], A01[2], A10[2], A11[2];
    float W00[2], W01[2], W10[2], W11[2];
    uint4 V00[2], V01[2], V10[2], V11[2];

    auto comp = [&](int pi) {
        const int s = pi & 1;
        const int l = pi >> 2, p = pi & 3;
        const int H = LVL_H[l], W = LVL_W[l], st = LVL_ST[l];
        const float fW = (float)W, fH = (float)H;
        const float* o2 = &ov[l * 2].x;
        const float ox = o2[p * 2 + 0];
        const float oy = o2[p * 2 + 1];
        const float x = (rx[l] + ox / fW) * fW - 0.5f;
        const float y = (ry[l] + oy / fH) * fH - 0.5f;
        const float x0f = floorf(x), y0f = floorf(y);
        const float wx = x - x0f, wy = y - y0f;
        const int ix0 = (int)x0f, iy0 = (int)y0f;
        const int ix1 = ix0 + 1,  iy1 = iy0 + 1;
        const float vx0 = (ix0 >= 0 && ix0 < W) ? 1.f : 0.f;
        const float vx1 = (ix1 >= 0 && ix1 < W) ? 1.f : 0.f;
        const float vy0 = (iy0 >= 0 && iy0 < H) ? 1.f : 0.f;
        const float vy1 = (iy1 >= 0 && iy1 < H) ? 1.f : 0.f;
        const int cx0 = min(max(ix0, 0), W - 1);
        const int cx1 = min(max(ix1, 0), W - 1);
        const int cy0 = min(max(iy0, 0), H - 1);
        const int cy1 = min(max(iy1, 0), H - 1);
        const float hx0 = (1.f - wx) * vx0, hx1 = wx * vx1;
        const float hy0 = (1.f - wy) * vy0, hy1 = wy * vy1;
        const int r0i = (st + cy0 * W) * 256;
        const int r1i = (st + cy1 * W) * 256;
        A00[s] = r0i + cx0 * 256;
        A01[s] = r0i + cx1 * 256;
        A10[s] = r1i + cx0 * 256;
        A11[s] = r1i + cx1 * 256;
        const float e = __expf(lg[pi] - mx);
        esum += e;
        W00[s] = e * hx0 * hy0; W01[s] = e * hx1 * hy0;
        W10[s] = e * hx0 * hy1; W11[s] = e * hx1 * hy1;
    };
    auto load = [&](int pi) {
        const int s = pi & 1;
        V00[s] = *(const uint4*)(vbase + A00[s]);
        V01[s] = *(const uint4*)(vbase + A01[s]);
        V10[s] = *(const uint4*)(vbase + A10[s]);
        V11[s] = *(const uint4*)(vbase + A11[s]);
    };

    comp(0); load(0);
#pragma unroll
    for (int pi = 0; pi < 16; pi++) {
        if (pi < 15) { comp(pi + 1); load(pi + 1); }
        const int s = pi & 1;
        acc8(acc, V00[s], W00[s]);
        acc8(acc, V01[s], W01[s]);
        acc8(acc, V10[s], W10[s]);
        acc8(acc, V11[s], W11[s]);
    }

    const float inv = 1.f / esum;
    uint4 o;
    o.x = pk2(acc[0] * inv, acc[1] * inv);
    o.y = pk2(acc[2] * inv, acc[3] * inv);
    o.z = pk2(acc[4] * inv, acc[5] * inv);
    o.w = pk2(acc[6] * inv, acc[7] * inv);
    *(uint4*)(mid + (size_t)bq * 256 + head * 32 + c8) = o;
}

// ======================= launch =======================
extern "C" void kernel_launch(void* const* d_in, const int* in_sizes, int n_in,
                              void* d_out, int out_size, void* d_ws, size_t ws_size,
                              hipStream_t stream)
{
    const float* query  = (const float*)d_in[0];
    const float* refp   = (const float*)d_in[1];
    const float* inflat = (const float*)d_in[2];
    const float* W_val  = (const float*)d_in[5];
    const float* b_val  = (const float*)d_in[6];
    const float* W_off  = (const float*)d_in[7];
    const float* b_off  = (const float*)d_in[8];
    const float* W_attn = (const float*)d_in[9];
    const float* b_attn = (const float*)d_in[10];
    const float* W_out  = (const float*)d_in[11];
    const float* b_out  = (const float*)d_in[12];
    float* out = (float*)d_out;

    char* ws = (char*)d_ws;
    ushort_t* value_bf = (ushort_t*)ws;                    // 11,141,120
    ushort_t* mid_bf   = (ushort_t*)(ws + 11141120);       // 11,141,120
    float*    offattn  = (float*)   (ws + 22282240);       // 33,423,360
    ushort_t* wvT      = (ushort_t*)(ws + 55705600);       // 131,072
    ushort_t* woutT    = (ushort_t*)(ws + 55836672);       // 131,072
    ushort_t* woaT     = (ushort_t*)(ws + 55967744);       // 196,608
    float*    bias_oa  = (float*)   (ws + 56164352);       // 1,536

    dim3 blk(256);
    pack_w<<<dim3(113), blk, 0, stream>>>(
        W_val, W_off, W_attn, W_out, b_off, b_attn, wvT, woaT, woutT, bias_oa);
    gemm_dual<<<dim3(850), blk, 0, stream>>>(
        inflat, wvT, b_val, value_bf, query, woaT, bias_oa, offattn);
    msda_sample_bf16<<<dim3(M_TOT / 8), blk, 0, stream>>>(
        value_bf, refp, offattn, mid_bf);
    gemm_out<<<dim3(340), blk, 0, stream>>>(
        mid_bf, woutT, b_out, out);
}